// Round 12
// baseline (702.225 us; speedup 1.0000x reference)
//
#include <hip/hip_runtime.h>
#include <cstdint>

#define NN 40000
#define EE 640000
#define GG 64

typedef short bf16x8 __attribute__((ext_vector_type(8)));
typedef float f32x4 __attribute__((ext_vector_type(4)));

// ---------- helpers ----------
__device__ __forceinline__ float lrelu(float x) { return x > 0.f ? x : 0.2f * x; }

__device__ __forceinline__ unsigned short f2bf(float f) {
    unsigned u = __float_as_uint(f);
    return (unsigned short)((u + 0x7FFFu + ((u >> 16) & 1u)) >> 16);
}
__device__ __forceinline__ float bf2f(unsigned short h) {
    return __uint_as_float(((unsigned)h) << 16);
}

__device__ __forceinline__ unsigned fenc(float x) {
    unsigned u = __float_as_uint(x);
    return (u & 0x80000000u) ? ~u : (u | 0x80000000u);
}
__device__ __forceinline__ float fdec(unsigned e) {
    unsigned u = (e & 0x80000000u) ? (e ^ 0x80000000u) : ~e;
    return __uint_as_float(u);
}
#define ENC_NEG_INF 0x007FFFFFu

// async global->LDS, 16B per lane (addrspacecast form — verified r7)
__device__ __forceinline__ void gload16(const void* g, void* l) {
    __builtin_amdgcn_global_load_lds(
        (const __attribute__((address_space(1))) unsigned int*)g,
        (__attribute__((address_space(3))) unsigned int*)l,
        16, 0, 0);
}

// per-lane GATv2 score partial: sum_c att[c]*lrelu(x[c]+xr[c]), with the
// LeakyReLU folded into the att factor: t*(t>0 ? av : 0.2*av)  (2 ops/term)
__device__ __forceinline__ float sc4(const float4 xv, const float4 xr,
                                     const float4 av, const float4 av5) {
    const float t0 = xv.x + xr.x, t1 = xv.y + xr.y;
    const float t2 = xv.z + xr.z, t3 = xv.w + xr.w;
    float s = t0 * (t0 > 0.f ? av.x : av5.x);
    s = fmaf(t1, (t1 > 0.f ? av.y : av5.y), s);
    s = fmaf(t2, (t2 > 0.f ? av.z : av5.z), s);
    s = fmaf(t3, (t3 > 0.f ? av.w : av5.w), s);
    return s;
}

// ---------- CSR build ----------
__global__ void k_init(int* deg, unsigned* gmax) {
    int i = blockIdx.x * blockDim.x + threadIdx.x;
    if (i < NN) deg[i] = 0;
    if (i < GG * 64) gmax[i] = ENC_NEG_INF;
}

__global__ void k_count(const int* __restrict__ dst, int* deg) {
    int e = blockIdx.x * blockDim.x + threadIdx.x;
    if (e < EE) atomicAdd(&deg[dst[e]], 1);
}

#define SCAN_T 1024
__global__ __launch_bounds__(SCAN_T) void k_scan(const int* __restrict__ deg,
                                                 int* row_ptr, int* cursor) {
    __shared__ int part[SCAN_T];
    const int t = threadIdx.x;
    const int CH = (NN + SCAN_T - 1) / SCAN_T;
    const int base = t * CH;
    int s = 0;
    for (int j = 0; j < CH; ++j) {
        int idx = base + j;
        if (idx < NN) s += deg[idx];
    }
    part[t] = s;
    __syncthreads();
    for (int off = 1; off < SCAN_T; off <<= 1) {
        int v = (t >= off) ? part[t - off] : 0;
        __syncthreads();
        part[t] += v;
        __syncthreads();
    }
    int run = (t == 0) ? 0 : part[t - 1];
    for (int j = 0; j < CH; ++j) {
        int idx = base + j;
        if (idx < NN) {
            row_ptr[idx] = run;
            cursor[idx]  = run;
            run += deg[idx];
        }
    }
    if (t == SCAN_T - 1) row_ptr[NN] = run;
}

__global__ void k_scatter(const int* __restrict__ src, const int* __restrict__ dst,
                          int* cursor, int* csr_src) {
    int e = blockIdx.x * blockDim.x + threadIdx.x;
    if (e < EE) {
        int p = atomicAdd(&cursor[dst[e]], 1);
        csr_src[p] = src[e];
    }
}

// ---------- bf16x2 split of a dense f32 array ----------
__global__ void k_xsplit(const float* __restrict__ x,
                         ushort* __restrict__ ah, ushort* __restrict__ am, int total4) {
    int i = blockIdx.x * blockDim.x + threadIdx.x;
    if (i >= total4) return;
    float4 v = ((const float4*)x)[i];
    ushort4 H, M;
    float* pv = &v.x;
    unsigned short* pH = &H.x; unsigned short* pM = &M.x;
#pragma unroll
    for (int j = 0; j < 4; ++j) {
        float a = pv[j];
        unsigned short h = f2bf(a);
        pH[j] = h;
        pM[j] = f2bf(a - bf2f(h));
    }
    ((ushort4*)ah)[i] = H;
    ((ushort4*)am)[i] = M;
}

// ---------- transpose + bf16x2 split: W[K][256] f32 -> combined Wt{h,m}[512][K] bf16 ----------
__global__ __launch_bounds__(256) void k_wsplit(const float* __restrict__ W, int K, int woff,
                                                ushort* __restrict__ th,
                                                ushort* __restrict__ tm) {
    __shared__ float t[32][33];
    const int n0 = blockIdx.x * 32;
    const int k0 = blockIdx.y * 32;
    const int tx = threadIdx.x;
    const int ty = threadIdx.y;
#pragma unroll
    for (int i = 0; i < 4; ++i) {
        int kl = ty * 4 + i;
        t[kl][tx] = W[(size_t)(k0 + kl) * 256 + n0 + tx];
    }
    __syncthreads();
#pragma unroll
    for (int i = 0; i < 4; ++i) {
        int nl = ty * 4 + i;
        float a = t[tx][nl];
        unsigned short h = f2bf(a);
        size_t o = (size_t)(woff + n0 + nl) * K + k0 + tx;
        th[o] = h;
        tm[o] = f2bf(a - bf2f(h));
    }
}

// ---------- bf16x2-split MFMA GEMM (combined): C[M][512] = A[M][K] @ B[K][512] ----------
// 128x128 tile, BK=32, 4 waves of 64x64, double-buffered LDS + 2-phase
// prefetch, XCD-aware tile swizzle (r10: +4% total). Products: hh + hm + mh.
#define GBM 128
#define GBK 32
#define NTILE 1252            // 313 bm x 4 bn
#define CHUNK 157             // ceil(1252/8)
__global__ __launch_bounds__(256, 2) void gemm2c(const ushort* __restrict__ Ah,
                                                 const ushort* __restrict__ Am,
                                                 const ushort* __restrict__ Bh,
                                                 const ushort* __restrict__ Bm,
                                                 float* __restrict__ C,
                                                 int M, int K) {
    const int b = blockIdx.x;
    const int t0 = (b & 7) * CHUNK + (b >> 3);
    if (t0 >= NTILE) return;                    // uniform whole-block exit
    const int bm = (t0 >> 2) * GBM;
    const int bn = (t0 & 3) * 128;

    __shared__ ushort sAh[2][GBM * GBK];
    __shared__ ushort sAm[2][GBM * GBK];
    __shared__ ushort sBh[2][GBM * GBK];
    __shared__ ushort sBm[2][GBM * GBK];
    const int tid  = threadIdx.x;
    const int lane = tid & 63;
    const int wv   = tid >> 6;
    const int wm   = wv & 1;
    const int wn   = wv >> 1;

    // wave -> staged tile (uniform selects)
    const ushort* gsrc = (wv == 0) ? Ah : (wv == 1) ? Am : (wv == 2) ? Bh : Bm;
    ushort* l0 = (wv == 0) ? sAh[0] : (wv == 1) ? sAm[0] : (wv == 2) ? sBh[0] : sBm[0];
    ushort* l1 = (wv == 0) ? sAh[1] : (wv == 1) ? sAm[1] : (wv == 2) ? sBh[1] : sBm[1];
    const int rowbase = (wv < 2) ? bm : bn;

    f32x4 acc[4][4];
#pragma unroll
    for (int i = 0; i < 4; ++i)
#pragma unroll
        for (int j = 0; j < 4; ++j)
            acc[i][j] = (f32x4){0.f, 0.f, 0.f, 0.f};

    const int rl = lane >> 2;       // staging row-in-group 0..15
    const int cs = lane & 3;        // staging LDS chunk slot 0..3
    const int fc = lane >> 4;       // fragment k-chunk 0..3
    const int fr = lane & 15;       // fragment row 0..15

    auto stage = [&](ushort* lb, int kt) {
        const int k0 = kt * GBK;
#pragma unroll
        for (int j = 0; j < 8; ++j) {
            const int lrow = j * 16 + rl;
            const int c    = cs ^ ((lrow >> 1) & 3);   // pre-swizzled source chunk
            int grow = rowbase + lrow;
            grow = (grow >= M) ? (M - 1) : grow;       // only A tiles can trigger
            gload16(gsrc + (size_t)grow * K + k0 + c * 8, lb + j * 512);
        }
    };

    stage(l0, 0);
    __syncthreads();                 // vmcnt(0) drain + barrier (prologue tile ready)

    const int nt = K / GBK;
    for (int t = 0; t < nt; ++t) {
        if (t + 1 < nt) stage((t & 1) ? l0 : l1, t + 1);   // issue next-tile loads

        const int bsel = t & 1;
        const ushort* pAh = sAh[bsel];
        const ushort* pAm = sAm[bsel];
        const ushort* pBh = sBh[bsel];
        const ushort* pBm = sBm[bsel];

        bf16x8 aH[4], aM[4], bH[4], bM[4];
#pragma unroll
        for (int mi = 0; mi < 4; ++mi) {
            const int row = wm * 64 + mi * 16 + fr;
            const int idx = row * 32 + (fc ^ ((row >> 1) & 3)) * 8;
            aH[mi] = *(const bf16x8*)&pAh[idx];
            aM[mi] = *(const bf16x8*)&pAm[idx];
        }
#pragma unroll
        for (int ni = 0; ni < 4; ++ni) {
            const int row = wn * 64 + ni * 16 + fr;
            const int idx = row * 32 + (fc ^ ((row >> 1) & 3)) * 8;
            bH[ni] = *(const bf16x8*)&pBh[idx];
            bM[ni] = *(const bf16x8*)&pBm[idx];
        }

#pragma unroll
        for (int mi = 0; mi < 4; ++mi)
#pragma unroll
            for (int ni = 0; ni < 4; ++ni) {
                f32x4 c0 = acc[mi][ni];
                c0 = __builtin_amdgcn_mfma_f32_16x16x32_bf16(aH[mi], bH[ni], c0, 0, 0, 0);
                c0 = __builtin_amdgcn_mfma_f32_16x16x32_bf16(aH[mi], bM[ni], c0, 0, 0, 0);
                c0 = __builtin_amdgcn_mfma_f32_16x16x32_bf16(aM[mi], bH[ni], c0, 0, 0, 0);
                acc[mi][ni] = c0;
            }
        __syncthreads();   // drains next-tile loads (hidden under compute) + barrier
    }

    // epilogue: C/D layout col=lane&15, row=(lane>>4)*4+reg ; C stride 512
#pragma unroll
    for (int mi = 0; mi < 4; ++mi) {
#pragma unroll
        for (int r = 0; r < 4; ++r) {
            const int row = bm + wm * 64 + mi * 16 + (lane >> 4) * 4 + r;
            if (row < M) {
#pragma unroll
                for (int ni = 0; ni < 4; ++ni) {
                    const int col = bn + wn * 64 + ni * 16 + (lane & 15);
                    C[(size_t)row * 512 + col] = acc[mi][ni][r];
                }
            }
        }
    }
}

// ---------- fused GATv2 edge-softmax aggregation ----------
// xlr[M][512]: cols 0..255 = xl, 256..511 = xr. One wave per node; lane l owns
// channels 4l..4l+3 (head = l>>4). 8-edge unroll (8 gathers in flight) +
// defer-max (THR=8) + folded lrelu*att.
// MODE 0: concat 4 heads + bias + LeakyReLU, bf16x2-split output
// MODE 1: mean over 4 heads (64 out) + bias, f32 output
template <int MODE>
__global__ __launch_bounds__(256) void k_aggregate(const float* __restrict__ xlr,
                                                   const float* __restrict__ att,
                                                   const float* __restrict__ bias,
                                                   const int* __restrict__ row_ptr,
                                                   const int* __restrict__ csr_src,
                                                   ushort* __restrict__ oh,
                                                   ushort* __restrict__ om,
                                                   float* __restrict__ of) {
    const int wave = threadIdx.x >> 6;
    const int lane = threadIdx.x & 63;
    const int node = blockIdx.x * 4 + wave;
    if (node >= NN) return;

    const float4 xri = ((const float4*)(xlr + (size_t)node * 512 + 256))[lane];
    const float4 av  = ((const float4*)att)[lane];
    const float4 av5 = {0.2f * av.x, 0.2f * av.y, 0.2f * av.z, 0.2f * av.w};

    float m = -INFINITY, d = 0.f;
    float a0 = 0.f, a1 = 0.f, a2 = 0.f, a3 = 0.f;

    const int start = row_ptr[node];
    const int endp  = row_ptr[node + 1];
    const int L = endp - start + 1;   // + self-loop as last virtual edge

    int i = 0;
    for (; i + 8 <= L; i += 8) {
        const int e0 = start + i;
        int s[8];
#pragma unroll
        for (int j = 0; j < 8; ++j)
            s[j] = (e0 + j < endp) ? csr_src[e0 + j] : node;
        const float4 x0 = ((const float4*)(xlr + (size_t)s[0] * 512))[lane];
        const float4 x1 = ((const float4*)(xlr + (size_t)s[1] * 512))[lane];
        const float4 x2 = ((const float4*)(xlr + (size_t)s[2] * 512))[lane];
        const float4 x3 = ((const float4*)(xlr + (size_t)s[3] * 512))[lane];
        const float4 x4 = ((const float4*)(xlr + (size_t)s[4] * 512))[lane];
        const float4 x5 = ((const float4*)(xlr + (size_t)s[5] * 512))[lane];
        const float4 x6 = ((const float4*)(xlr + (size_t)s[6] * 512))[lane];
        const float4 x7 = ((const float4*)(xlr + (size_t)s[7] * 512))[lane];
        float p0 = sc4(x0, xri, av, av5), p1 = sc4(x1, xri, av, av5);
        float p2 = sc4(x2, xri, av, av5), p3 = sc4(x3, xri, av, av5);
        float p4 = sc4(x4, xri, av, av5), p5 = sc4(x5, xri, av, av5);
        float p6 = sc4(x6, xri, av, av5), p7 = sc4(x7, xri, av, av5);
#pragma unroll
        for (int w = 1; w <= 8; w <<= 1) {
            p0 += __shfl_xor(p0, w); p1 += __shfl_xor(p1, w);
            p2 += __shfl_xor(p2, w); p3 += __shfl_xor(p3, w);
            p4 += __shfl_xor(p4, w); p5 += __shfl_xor(p5, w);
            p6 += __shfl_xor(p6, w); p7 += __shfl_xor(p7, w);
        }

        const float pm = fmaxf(fmaxf(fmaxf(p0, p1), fmaxf(p2, p3)),
                               fmaxf(fmaxf(p4, p5), fmaxf(p6, p7)));
        if (__all(pm <= m + 8.f)) {      // defer-max fast path (P bounded by e^8)
            const float f0 = __expf(p0 - m), f1 = __expf(p1 - m);
            const float f2 = __expf(p2 - m), f3 = __expf(p3 - m);
            const float f4 = __expf(p4 - m), f5 = __expf(p5 - m);
            const float f6 = __expf(p6 - m), f7 = __expf(p7 - m);
            d  += f0 + f1 + f2 + f3 + f4 + f5 + f6 + f7;
            a0 += f0 * x0.x + f1 * x1.x + f2 * x2.x + f3 * x3.x
                + f4 * x4.x + f5 * x5.x + f6 * x6.x + f7 * x7.x;
            a1 += f0 * x0.y + f1 * x1.y + f2 * x2.y + f3 * x3.y
                + f4 * x4.y + f5 * x5.y + f6 * x6.y + f7 * x7.y;
            a2 += f0 * x0.z + f1 * x1.z + f2 * x2.z + f3 * x3.z
                + f4 * x4.z + f5 * x5.z + f6 * x6.z + f7 * x7.z;
            a3 += f0 * x0.w + f1 * x1.w + f2 * x2.w + f3 * x3.w
                + f4 * x4.w + f5 * x5.w + f6 * x6.w + f7 * x7.w;
        } else {
            const float mn = fmaxf(m, pm);
            const float sc = __expf(m - mn);   // m=-inf first iter -> 0
            const float f0 = __expf(p0 - mn), f1 = __expf(p1 - mn);
            const float f2 = __expf(p2 - mn), f3 = __expf(p3 - mn);
            const float f4 = __expf(p4 - mn), f5 = __expf(p5 - mn);
            const float f6 = __expf(p6 - mn), f7 = __expf(p7 - mn);
            d  = d  * sc + f0 + f1 + f2 + f3 + f4 + f5 + f6 + f7;
            a0 = a0 * sc + f0 * x0.x + f1 * x1.x + f2 * x2.x + f3 * x3.x
                         + f4 * x4.x + f5 * x5.x + f6 * x6.x + f7 * x7.x;
            a1 = a1 * sc + f0 * x0.y + f1 * x1.y + f2 * x2.y + f3 * x3.y
                         + f4 * x4.y + f5 * x5.y + f6 * x6.y + f7 * x7.y;
            a2 = a2 * sc + f0 * x0.z + f1 * x1.z + f2 * x2.z + f3 * x3.z
                         + f4 * x4.z + f5 * x5.z + f6 * x6.z + f7 * x7.z;
            a3 = a3 * sc + f0 * x0.w + f1 * x1.w + f2 * x2.w + f3 * x3.w
                         + f4 * x4.w + f5 * x5.w + f6 * x6.w + f7 * x7.w;
            m = mn;
        }
    }
    for (; i < L; ++i) {   // tail (1..7 edges incl. self-loop)
        const int e0 = start + i;
        const int s0 = (e0 < endp) ? csr_src[e0] : node;
        const float4 x0 = ((const float4*)(xlr + (size_t)s0 * 512))[lane];
        float p0 = sc4(x0, xri, av, av5);
        p0 += __shfl_xor(p0, 1);
        p0 += __shfl_xor(p0, 2);
        p0 += __shfl_xor(p0, 4);
        p0 += __shfl_xor(p0, 8);
        if (__all(p0 <= m + 8.f)) {
            const float f0 = __expf(p0 - m);
            d += f0; a0 += f0 * x0.x; a1 += f0 * x0.y; a2 += f0 * x0.z; a3 += f0 * x0.w;
        } else {
            const float mn = fmaxf(m, p0);
            const float sc = __expf(m - mn);
            const float f0 = __expf(p0 - mn);
            d  = d  * sc + f0;
            a0 = a0 * sc + f0 * x0.x;
            a1 = a1 * sc + f0 * x0.y;
            a2 = a2 * sc + f0 * x0.z;
            a3 = a3 * sc + f0 * x0.w;
            m = mn;
        }
    }

    const float inv = 1.f / (d + 1e-16f);
    if (MODE == 0) {
        const int c = lane * 4;
        float v[4];
        v[0] = lrelu(a0 * inv + bias[c + 0]);
        v[1] = lrelu(a1 * inv + bias[c + 1]);
        v[2] = lrelu(a2 * inv + bias[c + 2]);
        v[3] = lrelu(a3 * inv + bias[c + 3]);
        ushort4 H, M4;
        unsigned short* pH = &H.x; unsigned short* pM = &M4.x;
#pragma unroll
        for (int j = 0; j < 4; ++j) {
            unsigned short h = f2bf(v[j]);
            pH[j] = h;
            pM[j] = f2bf(v[j] - bf2f(h));
        }
        const size_t o = (size_t)node * 64 + lane;   // ushort4 index
        ((ushort4*)oh)[o] = H;
        ((ushort4*)om)[o] = M4;
    } else {
        float v0 = a0 * inv, v1 = a1 * inv, v2 = a2 * inv, v3 = a3 * inv;
        v0 += __shfl_xor(v0, 16); v0 += __shfl_xor(v0, 32);
        v1 += __shfl_xor(v1, 16); v1 += __shfl_xor(v1, 32);
        v2 += __shfl_xor(v2, 16); v2 += __shfl_xor(v2, 32);
        v3 += __shfl_xor(v3, 16); v3 += __shfl_xor(v3, 32);
        if (lane < 16) {
            const int c = lane * 4;
            float4 o;
            o.x = v0 * 0.25f + bias[c + 0];
            o.y = v1 * 0.25f + bias[c + 1];
            o.z = v2 * 0.25f + bias[c + 2];
            o.w = v3 * 0.25f + bias[c + 3];
            ((float4*)(of + (size_t)node * 64))[lane] = o;
        }
    }
}

// ---------- global max pool (batch is sorted) ----------
#define PNB 32
__global__ __launch_bounds__(64) void k_pool(const float* __restrict__ h3,
                                             const int* __restrict__ batch,
                                             unsigned* gmax) {
    const int lane = threadIdx.x;
    const int start = blockIdx.x * PNB;
    if (start >= NN) return;
    const int end = min(start + PNB, NN);
    int curg = batch[start];
    float best = -INFINITY;
    for (int n = start; n < end; ++n) {
        int g = batch[n];
        if (g != curg) {
            atomicMax(&gmax[curg * 64 + lane], fenc(best));
            best = -INFINITY;
            curg = g;
        }
        best = fmaxf(best, h3[(size_t)n * 64 + lane]);
    }
    atomicMax(&gmax[curg * 64 + lane], fenc(best));
}

__global__ void k_decode(const unsigned* __restrict__ gmax, float* __restrict__ outg) {
    int i = blockIdx.x * blockDim.x + threadIdx.x;
    if (i < GG * 64) outg[i] = fdec(gmax[i]);
}

__global__ __launch_bounds__(128) void k_head(const float* __restrict__ g,
                                              const float* __restrict__ Wc,
                                              const float* __restrict__ bc,
                                              float* __restrict__ logits) {
    const int t = threadIdx.x;
    const int gr = t >> 1, o = t & 1;
    float s = bc[o];
    for (int c = 0; c < 64; ++c) s = fmaf(g[gr * 64 + c], Wc[c * 2 + o], s);
    logits[t] = s;
}

// ---------- launch ----------
extern "C" void kernel_launch(void* const* d_in, const int* in_sizes, int n_in,
                              void* d_out, int out_size, void* d_ws, size_t ws_size,
                              hipStream_t stream) {
    const float* x     = (const float*)d_in[0];
    const int*   ei    = (const int*)d_in[1];
    const int*   batch = (const int*)d_in[2];
    const float* Wl1 = (const float*)d_in[3];
    const float* Wr1 = (const float*)d_in[4];
    const float* att1 = (const float*)d_in[5];
    const float* b1  = (const float*)d_in[6];
    const float* Wl2 = (const float*)d_in[7];
    const float* Wr2 = (const float*)d_in[8];
    const float* att2 = (const float*)d_in[9];
    const float* b2  = (const float*)d_in[10];
    const float* Wl3 = (const float*)d_in[11];
    const float* Wr3 = (const float*)d_in[12];
    const float* att3 = (const float*)d_in[13];
    const float* b3  = (const float*)d_in[14];
    const float* Wc  = (const float*)d_in[15];
    const float* bc  = (const float*)d_in[16];
    float* out = (float*)d_out;   // [0..127]=logits, [128..4223]=g

    char* ws = (char*)d_ws;
    size_t off = 0;
    auto alloc = [&](size_t bytes) -> void* {
        void* p = ws + off;
        off += (bytes + 255) & ~(size_t)255;
        return p;
    };
    float*  xlr = (float*)alloc((size_t)NN * 512 * 4);    // combined xl|xr
    ushort* Ah  = (ushort*)alloc((size_t)NN * 256 * 2);
    ushort* Am  = (ushort*)alloc((size_t)NN * 256 * 2);
    // combined transposed weights per layer: [512][K] bf16, 2 planes
    const int Ksz[3] = {128, 256, 256};
    ushort* wtc[3][2];
    for (int l = 0; l < 3; ++l)
        for (int s = 0; s < 2; ++s)
            wtc[l][s] = (ushort*)alloc((size_t)512 * Ksz[l] * 2);
    int*   deg     = (int*)alloc((size_t)NN * 4);
    int*   cursor  = (int*)alloc((size_t)NN * 4);
    int*   row_ptr = (int*)alloc((size_t)(NN + 1) * 4);
    int*   csr_src = (int*)alloc((size_t)EE * 4);
    unsigned* gmax = (unsigned*)alloc((size_t)GG * 64 * 4);
    float* h3 = (float*)Ah;   // alias: Ah dead once layer-3 GEMM has read it
    if (off > ws_size) return;

    const int* esrc = ei;
    const int* edst = ei + EE;

    // CSR build (graph identical across layers)
    k_init<<<(NN + 255) / 256, 256, 0, stream>>>(deg, gmax);
    k_count<<<(EE + 255) / 256, 256, 0, stream>>>(edst, deg);
    k_scan<<<1, SCAN_T, 0, stream>>>(deg, row_ptr, cursor);
    k_scatter<<<(EE + 255) / 256, 256, 0, stream>>>(esrc, edst, cursor, csr_src);

    // splits
    k_xsplit<<<(NN * 128 / 4 + 255) / 256, 256, 0, stream>>>(x, Ah, Am, NN * 128 / 4);
    const float* Ws[6] = {Wl1, Wr1, Wl2, Wr2, Wl3, Wr3};
    for (int w = 0; w < 6; ++w) {
        const int l = w >> 1, woff = (w & 1) * 256, K = Ksz[l];
        dim3 g(8, K / 32), b(32, 8);
        k_wsplit<<<g, b, 0, stream>>>(Ws[w], K, woff, wtc[l][0], wtc[l][1]);
    }

    const int gemm_blocks = 8 * CHUNK;        // 1256 (XCD-swizzled tile space)
    const int agg_blocks = NN / 4;

    // Layer 1 (K=128)
    gemm2c<<<gemm_blocks, 256, 0, stream>>>(Ah, Am, wtc[0][0], wtc[0][1], xlr, NN, 128);
    k_aggregate<0><<<agg_blocks, 256, 0, stream>>>(xlr, att1, b1, row_ptr, csr_src,
                                                   Ah, Am, nullptr);
    // Layer 2 (K=256)
    gemm2c<<<gemm_blocks, 256, 0, stream>>>(Ah, Am, wtc[1][0], wtc[1][1], xlr, NN, 256);
    k_aggregate<0><<<agg_blocks, 256, 0, stream>>>(xlr, att2, b2, row_ptr, csr_src,
                                                   Ah, Am, nullptr);
    // Layer 3 (K=256), mean over heads
    gemm2c<<<gemm_blocks, 256, 0, stream>>>(Ah, Am, wtc[2][0], wtc[2][1], xlr, NN, 256);
    k_aggregate<1><<<agg_blocks, 256, 0, stream>>>(xlr, att3, b3, row_ptr, csr_src,
                                                   nullptr, nullptr, h3);

    // Pool + head
    k_pool<<<(NN + PNB - 1) / PNB, 64, 0, stream>>>(h3, batch, gmax);
    k_decode<<<(GG * 64 + 255) / 256, 256, 0, stream>>>(gmax, out + 128);
    k_head<<<1, 128, 0, stream>>>(out + 128, Wc, bc, out);
}